// Round 4
// baseline (718.213 us; speedup 1.0000x reference)
//
#include <hip/hip_runtime.h>

#define N_BATCH 2048
#define HW 49          // H*W = 7*7
#define CCH 512        // channels
#define PADQ 52        // padded q-dim (multiple of 4): attn rows 16B-aligned in LDS

typedef float f4 __attribute__((ext_vector_type(4)));

// ---------------------------------------------------------------------------
// Single fused kernel. 2 blocks per n (channel halves), 128 threads (2 waves),
// TWO channels per thread (c0 = h*256+tid and c0+128).
//
// Why 2 ch/thread: total DS-broadcast traffic = (#waves) x 49 rows x 13
// ds_read_b128. R3 (1 ch/thread, 8 waves/n) was DS-pipe bound at ~204 us.
// Halving the waves per n halves DS time (~102 us) at constant VALU FLOPs;
// DS, VALU and HBM all land near ~100 us.
//
// Channel pairing tid / tid+128 (not 2*tid/2*tid+1) keeps:
//   - D loads coalesced: two 256 B wave-transactions per q
//   - ylds stores at lane-stride 49 dwords (odd) -> conflict-free
// ---------------------------------------------------------------------------
__global__ __launch_bounds__(128, 1) void fused_bmm_lds_bcast2(
    const float* __restrict__ x, const float* __restrict__ D,
    const float* __restrict__ attn, const float* __restrict__ alpha_p,
    float* __restrict__ out)
{
    __shared__ float aT[HW * PADQ];     // 10,192 B, padded attn rows
    __shared__ float ylds[256 * HW];    // 50,176 B, y transpose staging

    const int bid = blockIdx.x;
    const int n   = bid >> 1;           // adjacent blocks share attn[n] via L2
    const int h   = bid & 1;
    const int tid = threadIdx.x;        // 0..127
    const int c0  = h * 256 + tid;      // channels c0 and c0+128

    // ---- stage attn[n] -> LDS (rows padded 49 -> 52, zeros) ----
    const float* an = attn + (size_t)n * (HW * HW);
    for (int j = tid; j < HW * PADQ; j += 128) {
        const int r  = j / PADQ;
        const int qq = j - r * PADQ;
        aT[j] = (qq < HW) ? an[r * HW + qq] : 0.0f;
    }

    // ---- this thread's two D columns into registers ----
    float d0[PADQ], d1[PADQ];
    d0[PADQ-3] = d0[PADQ-2] = d0[PADQ-1] = 0.0f;
    d1[PADQ-3] = d1[PADQ-2] = d1[PADQ-1] = 0.0f;
    const float* Dn = D + (size_t)n * (HW * CCH);
    #pragma unroll
    for (int q = 0; q < HW; ++q) {
        d0[q] = Dn[q * CCH + c0];
        d1[q] = Dn[q * CCH + c0 + 128];
    }

    __syncthreads();

    const f4* Af = (const f4*)aT;       // row p = Af[p*13 .. p*13+12]

    // dot of row BUF against both d-columns; 8 independent FMA chains
#define DOT(BUF, PP)                                                   \
    do {                                                               \
        float a0 = 0.f, a1 = 0.f, a2 = 0.f, a3 = 0.f;                  \
        float b0 = 0.f, b1 = 0.f, b2 = 0.f, b3 = 0.f;                  \
        _Pragma("unroll")                                              \
        for (int j = 0; j < PADQ / 4; ++j) {                           \
            a0 += BUF[j].x * d0[4*j+0];  b0 += BUF[j].x * d1[4*j+0];   \
            a1 += BUF[j].y * d0[4*j+1];  b1 += BUF[j].y * d1[4*j+1];   \
            a2 += BUF[j].z * d0[4*j+2];  b2 += BUF[j].z * d1[4*j+2];   \
            a3 += BUF[j].w * d0[4*j+3];  b3 += BUF[j].w * d1[4*j+3];   \
        }                                                              \
        ylds[tid * HW + (PP)]         = (a0 + a1) + (a2 + a3);         \
        ylds[(tid + 128) * HW + (PP)] = (b0 + b1) + (b2 + b3);         \
    } while (0)

    f4 Abuf[PADQ / 4], Bbuf[PADQ / 4];
    #pragma unroll
    for (int j = 0; j < PADQ / 4; ++j) Abuf[j] = Af[j];   // row 0

    // rows 0..47 in ping-pong pairs; row 48 as tail
    #pragma unroll 1
    for (int p = 0; p < HW - 1; p += 2) {
        #pragma unroll
        for (int j = 0; j < PADQ / 4; ++j) Bbuf[j] = Af[(p + 1) * (PADQ / 4) + j];
        DOT(Abuf, p);
        #pragma unroll
        for (int j = 0; j < PADQ / 4; ++j) Abuf[j] = Af[(p + 2) * (PADQ / 4) + j];
        DOT(Bbuf, p + 1);
    }
    DOT(Abuf, HW - 1);
#undef DOT

    __syncthreads();

    // ---- epilogue: flat coalesced out = x + alpha*y ----
    const float alpha = alpha_p[0];
    const size_t base = (size_t)n * (CCH * HW) + (size_t)h * (256 * HW);
    const f4* x4 = (const f4*)(x + base);
    f4*       o4 = (f4*)(out + base);
    const f4* y4 = (const f4*)ylds;
    for (int i = tid; i < (256 * HW) / 4; i += 128) {
        const f4 xv = x4[i];
        const f4 yv = y4[i];
        f4 ov = xv + alpha * yv;
        __builtin_nontemporal_store(ov, &o4[i]);
    }
}

extern "C" void kernel_launch(void* const* d_in, const int* in_sizes, int n_in,
                              void* d_out, int out_size, void* d_ws, size_t ws_size,
                              hipStream_t stream) {
    const float* x     = (const float*)d_in[0];   // [2048,512,7,7]
    const float* attn  = (const float*)d_in[1];   // [2048,49,49]
    const float* Dm    = (const float*)d_in[2];   // [2048,49,512]
    const float* alpha = (const float*)d_in[3];   // [1]
    float* out = (float*)d_out;
    (void)d_ws; (void)ws_size;

    fused_bmm_lds_bcast2<<<N_BATCH * 2, 128, 0, stream>>>(x, Dm, attn, alpha, out);
}